// Round 1
// baseline (449.232 us; speedup 1.0000x reference)
//
#include <hip/hip_runtime.h>

typedef unsigned short u16;
typedef short short8 __attribute__((ext_vector_type(8)));
typedef float f32x4 __attribute__((ext_vector_type(4)));
typedef float f32x16 __attribute__((ext_vector_type(16)));

#define LL 4096

__device__ __forceinline__ float bf2f(unsigned v) {
  unsigned q = v << 16;
  return __builtin_bit_cast(float, q);
}
__device__ __forceinline__ u16 f2bf(float f) {
  __bf16 h = (__bf16)f;                 // RNE
  return __builtin_bit_cast(unsigned short, h);
}

union S8u { uint2 u2[2]; uint4 u4; short8 s8; };

// ---------------- prep1: bf16 convert, transpose, row sumsq ----------------
__global__ void prep1(const float* __restrict__ x, u16* __restrict__ xbf,
                      u16* __restrict__ xT, float* __restrict__ sq) {
  int r = blockIdx.x;            // b*4096 + l
  int b = r >> 12, l = r & 4095;
  int t = threadIdx.x;
  float v = x[(size_t)r * 256 + t];
  u16 h = f2bf(v);
  xbf[(size_t)r * 256 + t] = h;
  xT[((size_t)b * 256 + t) * 4096 + l] = h;
  float s = v * v;
  #pragma unroll
  for (int off = 32; off; off >>= 1) s += __shfl_down(s, off, 64);
  __shared__ float red[4];
  if ((t & 63) == 0) red[t >> 6] = s;
  __syncthreads();
  if (t == 0) sq[r] = red[0] + red[1] + red[2] + red[3];
}

// ---------------- prep2: sinusoidal PE table ----------------
__global__ void prep2(float* __restrict__ pe) {
  int l = blockIdx.x, d = threadIdx.x;
  int i2 = d & ~1;
  float freq = expf((float)i2 * -0.03597789207803197f);  // -ln(10000)/256
  float arg = (float)l * freq;
  pe[(size_t)l * 256 + d] = (d & 1) ? cosf(arg) : sinf(arg);
}

// ---------------- main fused kernel ----------------
// block = (batch b, 64-row Q tile). 4 waves / 256 threads.
// wave w: mm1 -> S[all 64 rows][cols 16w..16w+15]; mm2 -> O[64][cols 64w..64w+63]
__global__ __launch_bounds__(256, 1) void tpe_main(
    const u16* __restrict__ xbf, const u16* __restrict__ xT,
    const float* __restrict__ sqv, const float* __restrict__ pe,
    const float* __restrict__ x, float* __restrict__ out) {
  __shared__ u16 Ks[64 * 264];    // K tile [j][d], stride 264 (pad for banks)
  __shared__ u16 VTs[256 * 72];   // x^T tile [d][j], stride 72
  __shared__ u16 Ps[2][64 * 68];  // P weights [i][j], stride 68, double buffered
  __shared__ float lred[4][64];
  __shared__ float linv[64];

  const int tid = threadIdx.x;
  const int w = tid >> 6;
  const int lane = tid & 63;
  const int l15 = lane & 15, l31 = lane & 31;
  const int q4 = lane >> 4;   // 0..3
  const int q2 = lane >> 5;   // 0..1

  // XCD swizzle: batch b pinned to an XCD pair so its 4MB of bf16 stays L2-hot
  const int blk = blockIdx.x;
  const int b = (blk & 7) >> 1;
  const int qt = ((blk >> 3) << 1) | (blk & 1);
  const int q0 = qt << 6;
  const long bL = (long)b * LL;

  // Q fragments in registers: A[m=lane&15][k=q4*8+j], reused for all 64 iters
  short8 qf[4][8];
  #pragma unroll
  for (int t = 0; t < 4; ++t) {
    const u16* qrow = xbf + (((long)(bL + q0 + 16 * t + l15)) << 8) + q4 * 8;
    #pragma unroll
    for (int s = 0; s < 8; ++s) qf[t][s] = *(const short8*)(qrow + 32 * s);
  }
  // -0.5*||q_i||^2 for this lane's C-layout rows
  float qa[4][4];
  #pragma unroll
  for (int t = 0; t < 4; ++t)
    #pragma unroll
    for (int r = 0; r < 4; ++r)
      qa[t][r] = -0.5f * sqv[bL + q0 + 16 * t + q4 * 4 + r];

  f32x16 oacc[2][2];
  #pragma unroll
  for (int i = 0; i < 2; ++i)
    #pragma unroll
    for (int j = 0; j < 2; ++j)
      #pragma unroll
      for (int k = 0; k < 16; ++k) oacc[i][j][k] = 0.f;
  float rs = 0.f;

  // register-staged global prefetch (tile 0)
  uint4 kreg[8], vreg[8];
  #pragma unroll
  for (int i = 0; i < 8; ++i) {
    int idx = tid + (i << 8);
    kreg[i] = *(const uint4*)(xbf + (((long)(bL + (idx >> 5))) << 8) + ((idx & 31) << 3));
    vreg[i] = *(const uint4*)(xT + (((long)(b * 256 + (idx >> 3))) << 12) + ((idx & 7) << 3));
  }

  for (int it = 0; it < 64; ++it) {
    const int pb = it & 1;
    const int j0 = it << 6;
    __syncthreads();  // previous iter done reading Ks/VTs
    // commit staged tile to LDS (padded strides)
    #pragma unroll
    for (int i = 0; i < 8; ++i) {
      int idx = tid + (i << 8);
      *(uint4*)(Ks + (idx >> 5) * 264 + ((idx & 31) << 3)) = kreg[i];
      *(uint4*)(VTs + (idx >> 3) * 72 + ((idx & 7) << 3)) = vreg[i];
    }
    float skv = -0.5f * sqv[bL + j0 + 16 * w + l15];
    __syncthreads();  // tiles visible
    // prefetch next tile (overlaps both matmul phases)
    if (it < 63) {
      int j1 = j0 + 64;
      #pragma unroll
      for (int i = 0; i < 8; ++i) {
        int idx = tid + (i << 8);
        kreg[i] = *(const uint4*)(xbf + (((long)(bL + j1 + (idx >> 5))) << 8) + ((idx & 31) << 3));
        vreg[i] = *(const uint4*)(xT + (((long)(b * 256 + (idx >> 3))) << 12) + j1 + ((idx & 7) << 3));
      }
    }
    // ---- mm1: S = Q K^T (16x16x32, 4 independent chains) ----
    f32x4 sacc[4];
    #pragma unroll
    for (int t = 0; t < 4; ++t)
      #pragma unroll
      for (int r = 0; r < 4; ++r) sacc[t][r] = 0.f;
    #pragma unroll
    for (int s = 0; s < 8; ++s) {
      short8 bfrag = *(const short8*)(Ks + (16 * w + l15) * 264 + 32 * s + q4 * 8);
      #pragma unroll
      for (int t = 0; t < 4; ++t)
        sacc[t] = __builtin_amdgcn_mfma_f32_16x16x32_bf16(qf[t][s], bfrag, sacc[t], 0, 0, 0);
    }
    // ---- exp(min(0, g - 0.5sqi - 0.5sqj)) -> P (bf16, LDS) ----
    u16* Pb = Ps[pb];
    #pragma unroll
    for (int t = 0; t < 4; ++t) {
      #pragma unroll
      for (int r = 0; r < 4; ++r) {
        float sv = sacc[t][r] + qa[t][r] + skv;
        sv = fminf(sv, 0.f);
        Pb[(16 * t + q4 * 4 + r) * 68 + 16 * w + l15] = f2bf(__expf(sv));
      }
    }
    __syncthreads();  // P ready for all waves
    // ---- rowsum partial from the same bf16 P (errors cancel in ratio) ----
    {
      const u16* pr = Pb + (tid & 63) * 68 + (w << 4);
      float p = 0.f;
      #pragma unroll
      for (int k = 0; k < 4; ++k) {
        uint2 uu = *(const uint2*)(pr + 4 * k);
        p += bf2f(uu.x & 0xffffu) + bf2f(uu.x >> 16) + bf2f(uu.y & 0xffffu) + bf2f(uu.y >> 16);
      }
      rs += p;
    }
    // ---- mm2: O += P V (32x32x16, 4 independent chains) ----
    #pragma unroll
    for (int s = 0; s < 4; ++s) {
      short8 a[2], bb[2];
      #pragma unroll
      for (int rb = 0; rb < 2; ++rb) {
        const u16* ap = Pb + (32 * rb + l31) * 68 + 16 * s + q2 * 8;
        S8u tmp;
        tmp.u2[0] = *(const uint2*)ap;
        tmp.u2[1] = *(const uint2*)(ap + 4);
        a[rb] = tmp.s8;
      }
      #pragma unroll
      for (int cb = 0; cb < 2; ++cb)
        bb[cb] = *(const short8*)(VTs + (64 * w + 32 * cb + l31) * 72 + 16 * s + q2 * 8);
      #pragma unroll
      for (int rb = 0; rb < 2; ++rb)
        #pragma unroll
        for (int cb = 0; cb < 2; ++cb)
          oacc[rb][cb] = __builtin_amdgcn_mfma_f32_32x32x16_bf16(a[rb], bb[cb], oacc[rb][cb], 0, 0, 0);
    }
  }

  // ---- epilogue: rowsum reduce, out = O/l + x + pe ----
  lred[w][tid & 63] = rs;
  __syncthreads();
  if (tid < 64) {
    float tv = lred[0][tid] + lred[1][tid] + lred[2][tid] + lred[3][tid];
    linv[tid] = 1.0f / tv;
  }
  __syncthreads();
  #pragma unroll
  for (int rb = 0; rb < 2; ++rb) {
    #pragma unroll
    for (int reg = 0; reg < 16; ++reg) {
      int row = 32 * rb + 4 * q2 + (reg & 3) + 8 * (reg >> 2);
      float li = linv[row];
      long gl = bL + q0 + row;
      #pragma unroll
      for (int cb = 0; cb < 2; ++cb) {
        int col = 64 * w + 32 * cb + l31;
        long off = (gl << 8) + col;
        out[off] = oacc[rb][cb][reg] * li + x[off] + pe[(((long)(q0 + row)) << 8) + col];
      }
    }
  }
}

extern "C" void kernel_launch(void* const* d_in, const int* in_sizes, int n_in,
                              void* d_out, int out_size, void* d_ws, size_t ws_size,
                              hipStream_t stream) {
  const float* x = (const float*)d_in[0];
  float* out = (float*)d_out;
  char* ws = (char*)d_ws;
  u16* xbf = (u16*)ws;                      //  8,388,608 B
  u16* xT = (u16*)(ws + 8388608);           //  8,388,608 B
  float* sq = (float*)(ws + 16777216);      //     65,536 B
  float* pe = (float*)(ws + 16842752);      //  4,194,304 B  (total ~20.1 MB)
  prep1<<<16384, 256, 0, stream>>>(x, xbf, xT, sq);
  prep2<<<4096, 256, 0, stream>>>(pe);
  tpe_main<<<256, 256, 0, stream>>>(xbf, xT, sq, pe, x, out);
}

// Round 2
// 226.607 us; speedup vs baseline: 1.9824x; 1.9824x over previous
//
#include <hip/hip_runtime.h>

typedef unsigned short u16;
typedef short short8 __attribute__((ext_vector_type(8)));
typedef float f32x4 __attribute__((ext_vector_type(4)));
typedef float f32x16 __attribute__((ext_vector_type(16)));

#define LL 4096
#define PSTR 136   // P row stride in u16 (272B: 16B-aligned, 68 dw %32 = 4 -> conflict-min)

__device__ __forceinline__ float bf2f(unsigned v) {
  unsigned q = v << 16;
  return __builtin_bit_cast(float, q);
}
__device__ __forceinline__ u16 f2bf(float f) {
  __bf16 h = (__bf16)f;                 // RNE
  return __builtin_bit_cast(unsigned short, h);
}

// ---------------- prep1: bf16 convert + row sumsq + tiled transpose ----------------
// block = 64 rows x 256 cols of one batch; 256 blocks total.
__global__ __launch_bounds__(256) void prep1(const float* __restrict__ x,
                                             u16* __restrict__ xbf,
                                             u16* __restrict__ xT,
                                             float* __restrict__ sq) {
  __shared__ u16 T[64 * 264];
  const int blk = blockIdx.x;
  const int b = blk >> 6, rt = blk & 63;
  const int r0 = rt << 6;
  const int tid = threadIdx.x;
  const int row = tid >> 2, q = tid & 3;   // 4 threads per row, 64 floats each
  const long grow = ((long)(b << 12) + r0 + row);
  const float* xr = x + (grow << 8) + (q << 6);
  u16* xbr = xbf + (grow << 8) + (q << 6);
  float s = 0.f;
  #pragma unroll
  for (int i = 0; i < 16; ++i) {
    float4 v = ((const float4*)xr)[i];
    s += v.x * v.x + v.y * v.y + v.z * v.z + v.w * v.w;
    uint2 p;
    p.x = (unsigned)f2bf(v.x) | ((unsigned)f2bf(v.y) << 16);
    p.y = (unsigned)f2bf(v.z) | ((unsigned)f2bf(v.w) << 16);
    ((uint2*)xbr)[i] = p;
    *(uint2*)(T + row * 264 + (q << 6) + (i << 2)) = p;
  }
  s += __shfl_down(s, 2);
  s += __shfl_down(s, 1);
  if (q == 0) sq[grow] = s;
  __syncthreads();
  // thread tid owns output d-row tid: xT[b][d=tid][r0..r0+63], coalesced 128B chunks
  unsigned wbuf[32];
  #pragma unroll
  for (int j = 0; j < 32; ++j) {
    unsigned a = T[(2 * j) * 264 + tid];
    unsigned c = T[(2 * j + 1) * 264 + tid];
    wbuf[j] = a | (c << 16);
  }
  u16* xtr = xT + (((long)(b << 8) + tid) << 12) + r0;
  #pragma unroll
  for (int k = 0; k < 8; ++k)
    ((uint4*)xtr)[k] = *(uint4*)(wbuf + 4 * k);
}

// ---------------- prep2: sinusoidal PE table ----------------
__global__ void prep2(float* __restrict__ pe) {
  int l = blockIdx.x, d = threadIdx.x;
  int i2 = d & ~1;
  float freq = expf((float)i2 * -0.03597789207803197f);  // -ln(10000)/256
  float arg = (float)l * freq;
  pe[(size_t)l * 256 + d] = (d & 1) ? cosf(arg) : sinf(arg);
}

// ---------------- main fused kernel ----------------
// 256 blocks x 512 threads (8 waves). Block = (batch, 64 Q rows).
// K-tile = 128 per iter, 32 iters, ONE barrier per iter.
// mm1: wave w -> S[64][16w..16w+15] (B-frags direct from global xbf)
// mm2: wave w -> O[64][32w..32w+31] (B-frags direct from global xT, A from LDS P)
__global__ __launch_bounds__(512, 2) void tpe_main(
    const u16* __restrict__ xbf, const u16* __restrict__ xT,
    const float* __restrict__ sqv, const float* __restrict__ pe,
    const float* __restrict__ x, float* __restrict__ out) {
  __shared__ u16 Ps[2][64 * PSTR];
  __shared__ float linv[64];

  const int tid = threadIdx.x;
  const int w = tid >> 6;
  const int lane = tid & 63;
  const int l15 = lane & 15, l31 = lane & 31;
  const int q4 = lane >> 4;   // 0..3
  const int q2 = lane >> 5;   // 0..1

  // XCD pinning: batch b lives on an XCD pair -> its 4MB (xbf+xT) stays L2-hot
  const int blk = blockIdx.x;
  const int b = (blk & 7) >> 1;
  const int qt = ((blk >> 3) << 1) | (blk & 1);
  const int q0 = qt << 6;
  const long bL = (long)b * LL;

  // Q fragments (all 64 rows) in registers: A[m=l15][k=8q4+j] per 32-d slab s
  short8 qf[4][8];
  #pragma unroll
  for (int t = 0; t < 4; ++t) {
    const u16* qrow = xbf + ((bL + q0 + 16 * t + l15) << 8) + 8 * q4;
    #pragma unroll
    for (int s = 0; s < 8; ++s) qf[t][s] = *(const short8*)(qrow + 32 * s);
  }
  float qa[4][4];
  #pragma unroll
  for (int t = 0; t < 4; ++t)
    #pragma unroll
    for (int r = 0; r < 4; ++r)
      qa[t][r] = -0.5f * sqv[bL + q0 + 16 * t + 4 * q4 + r];

  f32x16 oacc[2];
  #pragma unroll
  for (int rb = 0; rb < 2; ++rb)
    #pragma unroll
    for (int k = 0; k < 16; ++k) oacc[rb][k] = 0.f;
  float rs = 0.f;
  const int rsrow = tid >> 3, rscg = tid & 7;   // rowsum: 8 threads/row, 16 cols each

  for (int it = 0; it < 32; ++it) {
    const int j0 = it << 7;
    u16* Pb = Ps[it & 1];
    // ---- mm1: S = Q K^T, B-frags straight from global (L2) ----
    float skv = -0.5f * sqv[bL + j0 + 16 * w + l15];
    const u16* kbase = xbf + ((bL + j0 + 16 * w + l15) << 8) + 8 * q4;
    f32x4 sacc[4];
    #pragma unroll
    for (int t = 0; t < 4; ++t)
      #pragma unroll
      for (int r = 0; r < 4; ++r) sacc[t][r] = 0.f;
    #pragma unroll
    for (int s = 0; s < 8; ++s) {
      short8 bfrag = *(const short8*)(kbase + 32 * s);
      #pragma unroll
      for (int t = 0; t < 4; ++t)
        sacc[t] = __builtin_amdgcn_mfma_f32_16x16x32_bf16(qf[t][s], bfrag, sacc[t], 0, 0, 0);
    }
    // ---- P = exp(min(0, g - 0.5||q||^2 - 0.5||k||^2)) -> LDS (bf16) ----
    #pragma unroll
    for (int t = 0; t < 4; ++t)
      #pragma unroll
      for (int r = 0; r < 4; ++r) {
        float sv = sacc[t][r] + qa[t][r] + skv;
        sv = fminf(sv, 0.f);
        Pb[(16 * t + 4 * q4 + r) * PSTR + 16 * w + l15] = f2bf(__expf(sv));
      }
    __syncthreads();   // the ONLY barrier per iter
    // ---- rowsum from the same bf16 P (errors cancel in the ratio) ----
    {
      const u16* pr = Pb + rsrow * PSTR + rscg * 16;
      uint4 u0 = *(const uint4*)pr;
      uint4 u1 = *(const uint4*)(pr + 8);
      rs += bf2f(u0.x & 0xffffu) + bf2f(u0.x >> 16) + bf2f(u0.y & 0xffffu) + bf2f(u0.y >> 16)
          + bf2f(u0.z & 0xffffu) + bf2f(u0.z >> 16) + bf2f(u0.w & 0xffffu) + bf2f(u0.w >> 16)
          + bf2f(u1.x & 0xffffu) + bf2f(u1.x >> 16) + bf2f(u1.y & 0xffffu) + bf2f(u1.y >> 16)
          + bf2f(u1.z & 0xffffu) + bf2f(u1.z >> 16) + bf2f(u1.w & 0xffffu) + bf2f(u1.w >> 16);
    }
    // ---- mm2: O += P V, B-frags straight from global xT (L2) ----
    const u16* vbase = xT + (((long)(b << 8) + 32 * w + l31) << 12) + j0 + 8 * q2;
    #pragma unroll
    for (int s = 0; s < 8; ++s) {
      short8 bfrag = *(const short8*)(vbase + 16 * s);
      #pragma unroll
      for (int rb = 0; rb < 2; ++rb) {
        short8 afrag = *(const short8*)(Pb + (32 * rb + l31) * PSTR + 16 * s + 8 * q2);
        oacc[rb] = __builtin_amdgcn_mfma_f32_32x32x16_bf16(afrag, bfrag, oacc[rb], 0, 0, 0);
      }
    }
  }

  // ---- epilogue: rowsum reduce (8 consecutive lanes per row), out = O/l + x + pe ----
  rs += __shfl_down(rs, 4);
  rs += __shfl_down(rs, 2);
  rs += __shfl_down(rs, 1);
  if ((lane & 7) == 0) linv[8 * w + (lane >> 3)] = 1.0f / rs;
  __syncthreads();
  #pragma unroll
  for (int rb = 0; rb < 2; ++rb) {
    #pragma unroll
    for (int reg = 0; reg < 16; ++reg) {
      int row = 32 * rb + 4 * q2 + (reg & 3) + 8 * (reg >> 2);
      int col = 32 * w + l31;
      float li = linv[row];
      long off = ((bL + q0 + row) << 8) + col;
      out[off] = oacc[rb][reg] * li + x[off] + pe[(((long)(q0 + row)) << 8) + col];
    }
  }
}

extern "C" void kernel_launch(void* const* d_in, const int* in_sizes, int n_in,
                              void* d_out, int out_size, void* d_ws, size_t ws_size,
                              hipStream_t stream) {
  const float* x = (const float*)d_in[0];
  float* out = (float*)d_out;
  char* ws = (char*)d_ws;
  u16* xbf = (u16*)ws;                      //  8,388,608 B
  u16* xT = (u16*)(ws + 8388608);           //  8,388,608 B
  float* sq = (float*)(ws + 16777216);      //     65,536 B
  float* pe = (float*)(ws + 16842752);      //  4,194,304 B
  prep1<<<256, 256, 0, stream>>>(x, xbf, xT, sq);
  prep2<<<4096, 256, 0, stream>>>(pe);
  tpe_main<<<256, 512, 0, stream>>>(xbf, xT, sq, pe, x, out);
}

// Round 3
// 212.674 us; speedup vs baseline: 2.1123x; 1.0655x over previous
//
#include <hip/hip_runtime.h>

typedef unsigned char u8;
typedef float f32x4 __attribute__((ext_vector_type(4)));
typedef float f32x16 __attribute__((ext_vector_type(16)));

#define LL 4096
#define PSTR 136              // P row stride (bytes); 136=17*8 keeps b64 alignment
#define SCALE 16.0f           // x pre-scale before fp8 (x*16 ~ N(0,0.8), well in e4m3 range)
#define GSCALE (1.0f/256.0f)  // undo SCALE^2 on the gram

__device__ __forceinline__ long LCAST(uint2 v) { return __builtin_bit_cast(long, v); }

// ---------------- prep1: fp8 convert (x*16), row sumsq, tiled transpose ----------------
// 256 blocks x 256 thr; block = 64 rows of one batch. Fully coalesced in/out.
__global__ __launch_bounds__(256) void prep1(const float* __restrict__ x, u8* __restrict__ xbf,
                                             u8* __restrict__ xT, float* __restrict__ sq) {
  __shared__ u8 T[64 * 264];
  const int blk = blockIdx.x;
  const int b = blk >> 6, r0 = (blk & 63) << 6;
  const int tid = threadIdx.x;
  const long rowbase = (long)(b << 12) + r0;
  const float4* x4 = (const float4*)x + rowbase * 64;
  unsigned* xb4 = (unsigned*)xbf + rowbase * 64;
  #pragma unroll
  for (int i = 0; i < 16; ++i) {
    int idx = i * 256 + tid;                       // contiguous float4s -> coalesced
    float4 v = x4[idx];
    float s = v.x * v.x + v.y * v.y + v.z * v.z + v.w * v.w;
    #pragma unroll
    for (int o = 32; o; o >>= 1) s += __shfl_xor(s, o);
    if ((tid & 63) == 0) sq[rowbase + (idx >> 6)] = s;   // idx>>6 wave-uniform row
    int pk = __builtin_amdgcn_cvt_pk_fp8_f32(v.x * SCALE, v.y * SCALE, 0, false);
    pk = __builtin_amdgcn_cvt_pk_fp8_f32(v.z * SCALE, v.w * SCALE, pk, true);
    xb4[idx] = (unsigned)pk;
    *(unsigned*)(T + (idx >> 6) * 264 + (idx & 63) * 4) = (unsigned)pk;
  }
  __syncthreads();
  unsigned ob[16];
  #pragma unroll
  for (int jj = 0; jj < 16; ++jj) {
    unsigned b0 = T[(4 * jj + 0) * 264 + tid];
    unsigned b1 = T[(4 * jj + 1) * 264 + tid];
    unsigned b2 = T[(4 * jj + 2) * 264 + tid];
    unsigned b3 = T[(4 * jj + 3) * 264 + tid];
    ob[jj] = b0 | (b1 << 8) | (b2 << 16) | (b3 << 24);
  }
  u8* xtr = xT + (((long)(b << 8) + tid) << 12) + r0;   // thread tid owns d-row tid
  #pragma unroll
  for (int k = 0; k < 4; ++k) ((uint4*)xtr)[k] = *(uint4*)(ob + 4 * k);
}

// ---------------- prep2: sinusoidal PE table (pair per thread) ----------------
__global__ void prep2(float* __restrict__ pe) {
  int l = blockIdx.x, i = threadIdx.x;              // dims 2i, 2i+1
  float freq = __expf((float)(2 * i) * -0.03597789207803197f);  // -ln(10000)/256
  float arg = (float)l * freq;
  float s, c;
  sincosf(arg, &s, &c);
  *(float2*)(pe + ((size_t)l << 8) + 2 * i) = make_float2(s, c);
}

// ---------------- main fused kernel ----------------
// 256 blocks x 512 thr (8 waves, 1 block/CU). Block = (batch, 64 Q rows), K-tile 128, 32 iters.
// mm1 (16x16x32 fp8, operands swapped -> S^T): wave w does K-rows 16w..16w+15 vs all 64 Q.
// P packed to LDS as [i][j] via one b32/lane/t. mm2 (32x32x16 fp8): wave w -> O[64][32w..32w+31].
// K/V/sqk fragments double-buffered in registers, prefetched one iter ahead (L2-latency hiding).
__global__ __launch_bounds__(512, 2) void tpe_main(
    const u8* __restrict__ xbf, const u8* __restrict__ xT,
    const float* __restrict__ sqv, const float* __restrict__ pe,
    const float* __restrict__ x, float* __restrict__ out) {
  __shared__ u8 Ps[2][64 * PSTR];
  __shared__ float lred[8][64];
  __shared__ float linv[64];

  const int tid = threadIdx.x;
  const int w = tid >> 6;
  const int lane = tid & 63;
  const int l15 = lane & 15, l31 = lane & 31;
  const int q4 = lane >> 4;   // 0..3
  const int q2 = lane >> 5;   // 0..1

  // XCD pinning: batch -> XCD pair; fp8 working set (2 MB/batch) stays L2-hot
  const int blk = blockIdx.x;
  const int b = (blk & 7) >> 1;
  const int qt = ((blk >> 3) << 1) | (blk & 1);
  const int q0 = qt << 6;
  const long bL = (long)b * LL;

  // Q fragments (fp8): B-operand of mm1 (S^T). 64 VGPRs total.
  uint2 qf[4][8];
  #pragma unroll
  for (int t = 0; t < 4; ++t) {
    const u8* qrow = xbf + ((bL + q0 + 16 * t + l15) << 8) + 8 * q4;
    #pragma unroll
    for (int s = 0; s < 8; ++s) qf[t][s] = *(const uint2*)(qrow + 32 * s);
  }
  float qa[4];
  #pragma unroll
  for (int t = 0; t < 4; ++t) qa[t] = -0.5f * sqv[bL + q0 + 16 * t + l15];

  f32x16 oacc[2];
  #pragma unroll
  for (int rb = 0; rb < 2; ++rb)
    #pragma unroll
    for (int k = 0; k < 16; ++k) oacc[rb][k] = 0.f;
  float rsacc[4] = {0.f, 0.f, 0.f, 0.f};

  u8* Ps0 = Ps[0];
  u8* Ps1 = Ps[1];

  // prologue: load iter-0 K/V/sqk fragments
  uint2 kA[8], kB[8], vA[8], vB[8];
  float4 skA, skB;
  {
    const u8* kb = xbf + ((bL + 16 * w + l15) << 8) + 8 * q4;
    #pragma unroll
    for (int s = 0; s < 8; ++s) kA[s] = *(const uint2*)(kb + 32 * s);
    skA = *(const float4*)(sqv + bL + 16 * w + 4 * q4);
    const u8* vb = xT + (((long)(b << 8) + 32 * w + l31) << 12) + 8 * q2;
    #pragma unroll
    for (int s = 0; s < 8; ++s) vA[s] = *(const uint2*)(vb + 16 * s);
  }

#define TPE_ITER(KC, KN, VC, VN, SKC, SKN, IT, PBUF)                                        \
  {                                                                                         \
    const int j0 = (IT) << 7;                                                               \
    const int j1 = ((IT) < 31) ? (j0 + 128) : j0;                                           \
    { /* prefetch next-iter K + sqk (in flight across the whole iter) */                    \
      const u8* kb = xbf + ((bL + j1 + 16 * w + l15) << 8) + 8 * q4;                        \
      _Pragma("unroll")                                                                     \
      for (int s = 0; s < 8; ++s) KN[s] = *(const uint2*)(kb + 32 * s);                     \
      SKN = *(const float4*)(sqv + bL + j1 + 16 * w + 4 * q4);                              \
    }                                                                                       \
    f32x4 sacc[4];                                                                          \
    _Pragma("unroll")                                                                       \
    for (int t = 0; t < 4; ++t) {                                                           \
      sacc[t][0] = 0.f; sacc[t][1] = 0.f; sacc[t][2] = 0.f; sacc[t][3] = 0.f;               \
    }                                                                                       \
    _Pragma("unroll")                                                                       \
    for (int s = 0; s < 8; ++s) { /* S^T = K . Q^T : A=K frags, B=Q frags */                \
      long av = LCAST(KC[s]);                                                               \
      _Pragma("unroll")                                                                     \
      for (int t = 0; t < 4; ++t)                                                           \
        sacc[t] = __builtin_amdgcn_mfma_f32_16x16x32_fp8_fp8(av, LCAST(qf[t][s]), sacc[t], 0, 0, 0); \
    }                                                                                       \
    _Pragma("unroll")                                                                       \
    for (int t = 0; t < 4; ++t) { /* lane holds P[i=16t+l15][j = 16w+4q4 + 0..3] */         \
      float p0 = __expf(fminf(fmaf(sacc[t][0], GSCALE, qa[t] + SKC.x), 0.f));               \
      float p1 = __expf(fminf(fmaf(sacc[t][1], GSCALE, qa[t] + SKC.y), 0.f));               \
      float p2 = __expf(fminf(fmaf(sacc[t][2], GSCALE, qa[t] + SKC.z), 0.f));               \
      float p3 = __expf(fminf(fmaf(sacc[t][3], GSCALE, qa[t] + SKC.w), 0.f));               \
      rsacc[t] += (p0 + p1) + (p2 + p3);                                                    \
      int pk = __builtin_amdgcn_cvt_pk_fp8_f32(p0, p1, 0, false);                           \
      pk = __builtin_amdgcn_cvt_pk_fp8_f32(p2, p3, pk, true);                               \
      *(int*)((PBUF) + (16 * t + l15) * PSTR + 16 * w + 4 * q4) = pk;                       \
    }                                                                                       \
    __syncthreads();                                                                        \
    { /* mm2: O += P V ; V next-iter prefetch issued mid-loop */                            \
      const u8* vb = xT + (((long)(b << 8) + 32 * w + l31) << 12) + j1 + 8 * q2;            \
      _Pragma("unroll")                                                                     \
      for (int s = 0; s < 8; ++s) {                                                         \
        if (s == 4) {                                                                       \
          _Pragma("unroll")                                                                 \
          for (int ss = 0; ss < 8; ++ss) VN[ss] = *(const uint2*)(vb + 16 * ss);            \
        }                                                                                   \
        long a0 = *(const long*)((PBUF) + l31 * PSTR + 16 * s + 8 * q2);                    \
        long a1 = *(const long*)((PBUF) + (32 + l31) * PSTR + 16 * s + 8 * q2);             \
        long bv = LCAST(VC[s]);                                                             \
        oacc[0] = __builtin_amdgcn_mfma_f32_32x32x16_fp8_fp8(a0, bv, oacc[0], 0, 0, 0);     \
        oacc[1] = __builtin_amdgcn_mfma_f32_32x32x16_fp8_fp8(a1, bv, oacc[1], 0, 0, 0);     \
      }                                                                                     \
    }                                                                                       \
  }

  for (int it2 = 0; it2 < 16; ++it2) {
    TPE_ITER(kA, kB, vA, vB, skA, skB, 2 * it2, Ps0);
    TPE_ITER(kB, kA, vB, vA, skB, skA, 2 * it2 + 1, Ps1);
  }
#undef TPE_ITER

  // ---- epilogue: rowsum reduce; out = O*(1/16)/l + x + pe ----
  #pragma unroll
  for (int t = 0; t < 4; ++t) {
    float r = rsacc[t];
    r += __shfl_xor(r, 16);
    r += __shfl_xor(r, 32);
    if (lane < 16) lred[w][16 * t + lane] = r;
  }
  __syncthreads();
  if (tid < 64) {
    float s = 0.f;
    #pragma unroll
    for (int ww = 0; ww < 8; ++ww) s += lred[ww][tid];
    linv[tid] = 0.0625f / s;   // 1/16 undoes V pre-scale
  }
  __syncthreads();
  #pragma unroll
  for (int rb = 0; rb < 2; ++rb) {
    #pragma unroll
    for (int reg = 0; reg < 16; ++reg) {
      int row = 32 * rb + 4 * q2 + (reg & 3) + 8 * (reg >> 2);
      int col = 32 * w + l31;
      float li = linv[row];
      long off = ((bL + q0 + row) << 8) + col;
      out[off] = oacc[rb][reg] * li + x[off] + pe[(((long)(q0 + row)) << 8) + col];
    }
  }
}

extern "C" void kernel_launch(void* const* d_in, const int* in_sizes, int n_in,
                              void* d_out, int out_size, void* d_ws, size_t ws_size,
                              hipStream_t stream) {
  const float* x = (const float*)d_in[0];
  float* out = (float*)d_out;
  char* ws = (char*)d_ws;
  u8* xbf = (u8*)ws;                       // 4,194,304 B  (fp8 x, [b][l][d])
  u8* xT = (u8*)(ws + 4194304);            // 4,194,304 B  (fp8 x^T, [b][d][l])
  float* sq = (float*)(ws + 8388608);      //    65,536 B
  float* pe = (float*)(ws + 8454144);      // 4,194,304 B
  prep1<<<256, 256, 0, stream>>>(x, xbf, xT, sq);
  prep2<<<4096, 128, 0, stream>>>(pe);
  tpe_main<<<256, 512, 0, stream>>>(xbf, xT, sq, pe, x, out);
}